// Round 1
// baseline (1320.505 us; speedup 1.0000x reference)
//
#include <hip/hip_runtime.h>

// LlamaAttention: B=2, S=2048, HID=4096, NH=32, NKV=8, HD=128, GQA rep=4, RoPE, causal.
// Pipeline: qkv_gemm (bf16 MFMA, fp32 inputs converted in staging) -> rope -> flash_attn -> out_gemm.
// ws layout (bf16): Q[2,32,2048,128] | K[2,8,2048,128] | V[2,8,2048,128] | attn_out[2,2048,4096]  = 80 MB.

typedef __bf16 bf16x8 __attribute__((ext_vector_type(8)));
typedef float floatx4 __attribute__((ext_vector_type(4)));

#define S_LEN 2048
#define HIDN  4096
#define NH    32
#define NKV   8
#define HD    128

// ---------------------------------------------------------------------------
// QKV GEMM: C(m,n) = sum_k hs[m][k] * W[n][k]; n in [0,6144) selects Wq/Wk/Wv.
// 128x128 tile, BK=32, 4 waves of 64x64, mfma_f32_16x16x32_bf16.
// LDS rows padded to 40 bf16 (80B = 5x16B, 20-bank stride -> 2-way = free).
// ---------------------------------------------------------------------------
__global__ __launch_bounds__(256) void qkv_gemm(
    const float* __restrict__ A, const float* __restrict__ Wq,
    const float* __restrict__ Wk, const float* __restrict__ Wv,
    __bf16* __restrict__ Qb, __bf16* __restrict__ Kb, __bf16* __restrict__ Vb)
{
  __shared__ __bf16 As[128 * 40];
  __shared__ __bf16 Bs[128 * 40];
  const int tid  = threadIdx.x;
  const int wave = tid >> 6, lane = tid & 63;
  const int quad = lane >> 4, l16 = lane & 15;
  const int wrow = (wave >> 1) * 64, wcol = (wave & 1) * 64;
  const int m0 = blockIdx.y * 128;
  const int n0 = blockIdx.x * 128;

  const float* W; int wr0; int sel;
  if (n0 < 4096)      { W = Wq; wr0 = n0;        sel = 0; }
  else if (n0 < 5120) { W = Wk; wr0 = n0 - 4096; sel = 1; }
  else                { W = Wv; wr0 = n0 - 5120; sel = 2; }

  floatx4 acc[4][4];
  #pragma unroll
  for (int i = 0; i < 4; i++)
    #pragma unroll
    for (int j = 0; j < 4; j++) acc[i][j] = (floatx4){0.f, 0.f, 0.f, 0.f};

  for (int k0 = 0; k0 < HIDN; k0 += 32) {
    __syncthreads();  // WAR on LDS from previous iteration
    #pragma unroll
    for (int it = 0; it < 4; ++it) {
      int c = tid + it * 256;           // 1024 float4 chunks: 128 rows x 8
      int row = c >> 3, c4 = (c & 7) * 4;
      float4 va = *(const float4*)(A + (size_t)(m0 + row) * HIDN + k0 + c4);
      __bf16* da = &As[row * 40 + c4];
      da[0] = (__bf16)va.x; da[1] = (__bf16)va.y; da[2] = (__bf16)va.z; da[3] = (__bf16)va.w;
      float4 vb = *(const float4*)(W + (size_t)(wr0 + row) * HIDN + k0 + c4);
      __bf16* db = &Bs[row * 40 + c4];
      db[0] = (__bf16)vb.x; db[1] = (__bf16)vb.y; db[2] = (__bf16)vb.z; db[3] = (__bf16)vb.w;
    }
    __syncthreads();
    bf16x8 af[4], bfr[4];
    #pragma unroll
    for (int i = 0; i < 4; i++)
      af[i] = *(const bf16x8*)&As[(wrow + i * 16 + l16) * 40 + quad * 8];
    #pragma unroll
    for (int j = 0; j < 4; j++)
      bfr[j] = *(const bf16x8*)&Bs[(wcol + j * 16 + l16) * 40 + quad * 8];
    #pragma unroll
    for (int i = 0; i < 4; i++)
      #pragma unroll
      for (int j = 0; j < 4; j++)
        acc[i][j] = __builtin_amdgcn_mfma_f32_16x16x32_bf16(af[i], bfr[j], acc[i][j], 0, 0, 0);
  }

  // Epilogue: C/D layout col=lane&15, row=quad*4+r (m89-verified). Scatter to (B,H,S,HD).
  #pragma unroll
  for (int i = 0; i < 4; i++) {
    #pragma unroll
    for (int j = 0; j < 4; j++) {
      #pragma unroll
      for (int r = 0; r < 4; r++) {
        int m = m0 + wrow + i * 16 + quad * 4 + r;
        int n = n0 + wcol + j * 16 + l16;
        __bf16 v = (__bf16)acc[i][j][r];
        int b = m >> 11, s = m & (S_LEN - 1);
        if (sel == 0) {
          int h = n >> 7, d = n & 127;
          Qb[(((size_t)b * NH + h) * S_LEN + s) * HD + d] = v;
        } else {
          int nl = n - (sel == 1 ? 4096 : 5120);
          int h = nl >> 7, d = nl & 127;
          __bf16* dst = (sel == 1) ? Kb : Vb;
          dst[(((size_t)b * NKV + h) * S_LEN + s) * HD + d] = v;
        }
      }
    }
  }
}

// ---------------------------------------------------------------------------
// RoPE in-place on bf16 Q and K. One thread per (b,h,s,d<64) pair.
// cos/sin halves are identical (emb = concat([ang, ang])).
// ---------------------------------------------------------------------------
__global__ __launch_bounds__(256) void rope_kernel(
    __bf16* __restrict__ Qb, __bf16* __restrict__ Kb,
    const float* __restrict__ cosp, const float* __restrict__ sinp)
{
  size_t i = (size_t)blockIdx.x * 256 + threadIdx.x;
  const size_t QP = (size_t)2 * NH * S_LEN * 64;  // 8388608 Q pairs
  __bf16* buf; int H; size_t t;
  if (i < QP) { buf = Qb; H = NH;  t = i; }
  else        { buf = Kb; H = NKV; t = i - QP; }
  int d = (int)(t & 63);
  int s = (int)((t >> 6) & (S_LEN - 1));
  size_t rest = t >> 17;            // / (S*64)
  int h = (int)(rest % H);
  int b = (int)(rest / H);
  size_t base = (((size_t)b * H + h) * S_LEN + s) * HD;
  float q0 = (float)buf[base + d];
  float q1 = (float)buf[base + d + 64];
  float c  = cosp[((size_t)b * S_LEN + s) * HD + d];
  float sn = sinp[((size_t)b * S_LEN + s) * HD + d];
  buf[base + d]      = (__bf16)(q0 * c - q1 * sn);
  buf[base + d + 64] = (__bf16)(q1 * c + q0 * sn);
}

// ---------------------------------------------------------------------------
// Flash attention, causal, GQA. Block = 64 q-rows of one (b,h); 4 waves x 16 rows.
// K/V tiles of 64 kv. P transform C-layout -> LDS -> A-layout (m120 pattern).
// V staged transposed (VT[d][kv]) for contiguous PV B-frag reads.
// ---------------------------------------------------------------------------
__global__ __launch_bounds__(256) void flash_attn(
    const __bf16* __restrict__ Q, const __bf16* __restrict__ Kc,
    const __bf16* __restrict__ Vc, __bf16* __restrict__ Out)
{
  __shared__ __bf16 Qs[64 * 136];     // pad 136: 272B stride -> 2-way = free
  __shared__ __bf16 Ks[64 * 136];
  __shared__ __bf16 VT[128 * 72];     // 144B stride -> 2-way = free
  __shared__ __bf16 Ps[4 * 16 * 72];  // per-wave P buffer
  const int tid  = threadIdx.x;
  const int wave = tid >> 6, lane = tid & 63;
  const int quad = lane >> 4, l16 = lane & 15;
  const int qb = blockIdx.x;          // q tile of 64
  const int h  = blockIdx.y;
  const int b  = blockIdx.z;
  const int kvh = h >> 2;             // N_REP = 4
  const size_t qbase = (((size_t)b * NH + h) * S_LEN + (size_t)qb * 64) * HD;
  const size_t kbase = ((size_t)b * NKV + kvh) * S_LEN * HD;

  // Load Q tile (64 x 128)
  #pragma unroll
  for (int it = 0; it < 4; ++it) {
    int c = tid + it * 256;
    int row = c >> 4, d0 = (c & 15) * 8;
    *(bf16x8*)&Qs[row * 136 + d0] = *(const bf16x8*)&Q[qbase + (size_t)row * HD + d0];
  }

  floatx4 o[8];
  #pragma unroll
  for (int j = 0; j < 8; j++) o[j] = (floatx4){0.f, 0.f, 0.f, 0.f};
  float m_i[4], l_i[4];
  #pragma unroll
  for (int r = 0; r < 4; r++) { m_i[r] = -3.0e38f; l_i[r] = 0.f; }

  const float scale = 0.08838834764831845f;  // 128^-0.5
  const int row_q = qb * 64 + wave * 16 + quad * 4;  // + r

  for (int kj = 0; kj <= qb; ++kj) {
    __syncthreads();  // previous iteration's LDS reads done (also orders Qs load on iter 0)
    #pragma unroll
    for (int it = 0; it < 4; ++it) {  // K tile
      int c = tid + it * 256;
      int row = c >> 4, d0 = (c & 15) * 8;
      *(bf16x8*)&Ks[row * 136 + d0] =
          *(const bf16x8*)&Kc[kbase + (size_t)(kj * 64 + row) * HD + d0];
    }
    #pragma unroll
    for (int it = 0; it < 4; ++it) {  // V tile, transposed into LDS (conflict-free stores)
      int c = tid + it * 256;
      int row = c & 63, dc = c >> 6;
      bf16x8 v = *(const bf16x8*)&Vc[kbase + (size_t)(kj * 64 + row) * HD + dc * 8];
      #pragma unroll
      for (int u = 0; u < 8; ++u) VT[(dc * 8 + u) * 72 + row] = v[u];
    }
    __syncthreads();

    // Scores: wave's 16 q-rows x 64 kv, K-dim 128 = 4 MFMA k-steps
    floatx4 s[4];
    #pragma unroll
    for (int j = 0; j < 4; j++) s[j] = (floatx4){0.f, 0.f, 0.f, 0.f};
    #pragma unroll
    for (int kk = 0; kk < 4; kk++) {
      bf16x8 aq = *(const bf16x8*)&Qs[(wave * 16 + l16) * 136 + kk * 32 + quad * 8];
      #pragma unroll
      for (int j = 0; j < 4; j++) {
        bf16x8 bk = *(const bf16x8*)&Ks[(j * 16 + l16) * 136 + kk * 32 + quad * 8];
        s[j] = __builtin_amdgcn_mfma_f32_16x16x32_bf16(aq, bk, s[j], 0, 0, 0);
      }
    }

    const bool diag = (kj == qb);
    float p[4][4], rm[4];
    #pragma unroll
    for (int r = 0; r < 4; r++) {
      float mx = -3.0e38f;
      #pragma unroll
      for (int j = 0; j < 4; j++) {
        float v = s[j][r] * scale;
        if (diag) {
          int ki = kj * 64 + j * 16 + l16;
          if (ki > row_q + r) v = -1.0e9f;   // causal mask (ref adds -1e9)
        }
        p[j][r] = v;
        mx = fmaxf(mx, v);
      }
      #pragma unroll
      for (int off = 1; off < 16; off <<= 1) mx = fmaxf(mx, __shfl_xor(mx, off, 64));
      rm[r] = mx;
    }
    float alpha[4];
    #pragma unroll
    for (int r = 0; r < 4; r++) {
      float mn = fmaxf(m_i[r], rm[r]);
      alpha[r] = __expf(m_i[r] - mn);
      m_i[r] = mn;
      float rs = 0.f;
      #pragma unroll
      for (int j = 0; j < 4; j++) {
        float e = __expf(p[j][r] - mn);
        p[j][r] = e;
        rs += e;
      }
      #pragma unroll
      for (int off = 1; off < 16; off <<= 1) rs += __shfl_xor(rs, off, 64);
      l_i[r] = l_i[r] * alpha[r] + rs;
    }
    #pragma unroll
    for (int j = 0; j < 8; j++)
      #pragma unroll
      for (int r = 0; r < 4; r++) o[j][r] *= alpha[r];

    // P: C-layout -> per-wave LDS -> A-layout (wave-internal; DS pipe is in-order)
    #pragma unroll
    for (int j = 0; j < 4; j++)
      #pragma unroll
      for (int r = 0; r < 4; r++)
        Ps[wave * 16 * 72 + (quad * 4 + r) * 72 + j * 16 + l16] = (__bf16)p[j][r];

    // PV: O(16x128) += P(16x64) * V(64x128), 2 k-steps
    #pragma unroll
    for (int kk = 0; kk < 2; kk++) {
      bf16x8 ap = *(const bf16x8*)&Ps[wave * 16 * 72 + l16 * 72 + kk * 32 + quad * 8];
      #pragma unroll
      for (int ct = 0; ct < 8; ct++) {
        bf16x8 bv = *(const bf16x8*)&VT[(ct * 16 + l16) * 72 + kk * 32 + quad * 8];
        o[ct] = __builtin_amdgcn_mfma_f32_16x16x32_bf16(ap, bv, o[ct], 0, 0, 0);
      }
    }
  }

  // Epilogue: write attn_out[b][s][h*128+d] bf16
  #pragma unroll
  for (int ct = 0; ct < 8; ct++) {
    #pragma unroll
    for (int r = 0; r < 4; r++) {
      int qi = row_q + r;
      int d  = ct * 16 + l16;
      float v = o[ct][r] / l_i[r];
      Out[((size_t)b * S_LEN + qi) * HIDN + h * HD + d] = (__bf16)v;
    }
  }
}

// ---------------------------------------------------------------------------
// Output GEMM: out(m,n) = sum_k attn_out[m][k] * Wo[n][k]; bf16 A, fp32 Wo->bf16.
// ---------------------------------------------------------------------------
__global__ __launch_bounds__(256) void out_gemm(
    const __bf16* __restrict__ A, const float* __restrict__ Wo,
    float* __restrict__ C)
{
  __shared__ __bf16 As[128 * 40];
  __shared__ __bf16 Bs[128 * 40];
  const int tid  = threadIdx.x;
  const int wave = tid >> 6, lane = tid & 63;
  const int quad = lane >> 4, l16 = lane & 15;
  const int wrow = (wave >> 1) * 64, wcol = (wave & 1) * 64;
  const int m0 = blockIdx.y * 128;
  const int n0 = blockIdx.x * 128;

  floatx4 acc[4][4];
  #pragma unroll
  for (int i = 0; i < 4; i++)
    #pragma unroll
    for (int j = 0; j < 4; j++) acc[i][j] = (floatx4){0.f, 0.f, 0.f, 0.f};

  for (int k0 = 0; k0 < HIDN; k0 += 32) {
    __syncthreads();
    #pragma unroll
    for (int it = 0; it < 2; ++it) {  // A tile: 512 bf16x8 chunks
      int c = tid + it * 256;
      int row = c >> 2, c8 = (c & 3) * 8;
      *(bf16x8*)&As[row * 40 + c8] =
          *(const bf16x8*)(A + (size_t)(m0 + row) * HIDN + k0 + c8);
    }
    #pragma unroll
    for (int it = 0; it < 4; ++it) {  // Wo tile: fp32 -> bf16
      int c = tid + it * 256;
      int row = c >> 3, c4 = (c & 7) * 4;
      float4 vb = *(const float4*)(Wo + (size_t)(n0 + row) * HIDN + k0 + c4);
      __bf16* db = &Bs[row * 40 + c4];
      db[0] = (__bf16)vb.x; db[1] = (__bf16)vb.y; db[2] = (__bf16)vb.z; db[3] = (__bf16)vb.w;
    }
    __syncthreads();
    bf16x8 af[4], bfr[4];
    #pragma unroll
    for (int i = 0; i < 4; i++)
      af[i] = *(const bf16x8*)&As[(wrow + i * 16 + l16) * 40 + quad * 8];
    #pragma unroll
    for (int j = 0; j < 4; j++)
      bfr[j] = *(const bf16x8*)&Bs[(wcol + j * 16 + l16) * 40 + quad * 8];
    #pragma unroll
    for (int i = 0; i < 4; i++)
      #pragma unroll
      for (int j = 0; j < 4; j++)
        acc[i][j] = __builtin_amdgcn_mfma_f32_16x16x32_bf16(af[i], bfr[j], acc[i][j], 0, 0, 0);
  }

  #pragma unroll
  for (int i = 0; i < 4; i++)
    #pragma unroll
    for (int j = 0; j < 4; j++)
      #pragma unroll
      for (int r = 0; r < 4; r++) {
        int m = m0 + wrow + i * 16 + quad * 4 + r;
        int n = n0 + wcol + j * 16 + l16;
        C[(size_t)m * HIDN + n] = acc[i][j][r];
      }
}

// ---------------------------------------------------------------------------
extern "C" void kernel_launch(void* const* d_in, const int* in_sizes, int n_in,
                              void* d_out, int out_size, void* d_ws, size_t ws_size,
                              hipStream_t stream)
{
  const float* hs   = (const float*)d_in[0];
  const float* cosp = (const float*)d_in[1];
  const float* sinp = (const float*)d_in[2];
  // d_in[3] = attention_mask: exactly causal -1e9, applied analytically in flash_attn
  const float* Wq   = (const float*)d_in[4];
  const float* Wk   = (const float*)d_in[5];
  const float* Wv   = (const float*)d_in[6];
  const float* Wo   = (const float*)d_in[7];
  float* out = (float*)d_out;

  __bf16* Qb = (__bf16*)d_ws;                          // 16,777,216 elems
  __bf16* Kb = Qb + (size_t)2 * NH  * S_LEN * HD;      //  4,194,304
  __bf16* Vb = Kb + (size_t)2 * NKV * S_LEN * HD;      //  4,194,304
  __bf16* AO = Vb + (size_t)2 * NKV * S_LEN * HD;      // 16,777,216  (total 80 MB)

  qkv_gemm<<<dim3(48, 32), 256, 0, stream>>>(hs, Wq, Wk, Wv, Qb, Kb, Vb);
  rope_kernel<<<40960, 256, 0, stream>>>(Qb, Kb, cosp, sinp);
  flash_attn<<<dim3(32, NH, 2), 256, 0, stream>>>(Qb, Kb, Vb, AO);
  out_gemm<<<dim3(32, 32), 256, 0, stream>>>(AO, Wo, out);
}

// Round 2
// 1019.576 us; speedup vs baseline: 1.2952x; 1.2952x over previous
//
#include <hip/hip_runtime.h>

// LlamaAttention: B=2, S=2048, HID=4096, NH=32, NKV=8, HD=128, GQA rep=4, RoPE, causal.
// Pipeline: qkv_gemm (bf16 MFMA, V written transposed) -> rope -> flash_attn -> out_gemm.
// ws layout (bf16): Q[2,32,2048,128] | K[2,8,2048,128] | Vt[2,8,128,2048] | attn_out[2,2048,4096] = 80 MB.

typedef __bf16 bf16x8 __attribute__((ext_vector_type(8)));
typedef float floatx4 __attribute__((ext_vector_type(4)));

#define S_LEN 2048
#define HIDN  4096
#define NH    32
#define NKV   8
#define HD    128

// ---------------------------------------------------------------------------
// QKV GEMM: C(m,n) = sum_k hs[m][k] * W[n][k]; n in [0,6144) selects Wq/Wk/Wv.
// 128x128 tile, BK=32, 4 waves of 64x64, mfma_f32_16x16x32_bf16.
// V is written TRANSPOSED: Vt[b][kvh][d][s] so flash_attn can stage V^T with b128s.
// ---------------------------------------------------------------------------
__global__ __launch_bounds__(256) void qkv_gemm(
    const float* __restrict__ A, const float* __restrict__ Wq,
    const float* __restrict__ Wk, const float* __restrict__ Wv,
    __bf16* __restrict__ Qb, __bf16* __restrict__ Kb, __bf16* __restrict__ Vt)
{
  __shared__ __bf16 As[128 * 40];
  __shared__ __bf16 Bs[128 * 40];
  const int tid  = threadIdx.x;
  const int wave = tid >> 6, lane = tid & 63;
  const int quad = lane >> 4, l16 = lane & 15;
  const int wrow = (wave >> 1) * 64, wcol = (wave & 1) * 64;
  const int m0 = blockIdx.y * 128;
  const int n0 = blockIdx.x * 128;

  const float* W; int wr0; int sel;
  if (n0 < 4096)      { W = Wq; wr0 = n0;        sel = 0; }
  else if (n0 < 5120) { W = Wk; wr0 = n0 - 4096; sel = 1; }
  else                { W = Wv; wr0 = n0 - 5120; sel = 2; }

  floatx4 acc[4][4];
  #pragma unroll
  for (int i = 0; i < 4; i++)
    #pragma unroll
    for (int j = 0; j < 4; j++) acc[i][j] = (floatx4){0.f, 0.f, 0.f, 0.f};

  for (int k0 = 0; k0 < HIDN; k0 += 32) {
    __syncthreads();  // WAR on LDS from previous iteration
    #pragma unroll
    for (int it = 0; it < 4; ++it) {
      int c = tid + it * 256;           // 1024 float4 chunks: 128 rows x 8
      int row = c >> 3, c4 = (c & 7) * 4;
      float4 va = *(const float4*)(A + (size_t)(m0 + row) * HIDN + k0 + c4);
      __bf16* da = &As[row * 40 + c4];
      da[0] = (__bf16)va.x; da[1] = (__bf16)va.y; da[2] = (__bf16)va.z; da[3] = (__bf16)va.w;
      float4 vb = *(const float4*)(W + (size_t)(wr0 + row) * HIDN + k0 + c4);
      __bf16* db = &Bs[row * 40 + c4];
      db[0] = (__bf16)vb.x; db[1] = (__bf16)vb.y; db[2] = (__bf16)vb.z; db[3] = (__bf16)vb.w;
    }
    __syncthreads();
    bf16x8 af[4], bfr[4];
    #pragma unroll
    for (int i = 0; i < 4; i++)
      af[i] = *(const bf16x8*)&As[(wrow + i * 16 + l16) * 40 + quad * 8];
    #pragma unroll
    for (int j = 0; j < 4; j++)
      bfr[j] = *(const bf16x8*)&Bs[(wcol + j * 16 + l16) * 40 + quad * 8];
    #pragma unroll
    for (int i = 0; i < 4; i++)
      #pragma unroll
      for (int j = 0; j < 4; j++)
        acc[i][j] = __builtin_amdgcn_mfma_f32_16x16x32_bf16(af[i], bfr[j], acc[i][j], 0, 0, 0);
  }

  // Epilogue: C/D layout col=lane&15, row=quad*4+r (m89-verified).
  #pragma unroll
  for (int i = 0; i < 4; i++) {
    #pragma unroll
    for (int j = 0; j < 4; j++) {
      #pragma unroll
      for (int r = 0; r < 4; r++) {
        int m = m0 + wrow + i * 16 + quad * 4 + r;
        int n = n0 + wcol + j * 16 + l16;
        __bf16 v = (__bf16)acc[i][j][r];
        int b = m >> 11, s = m & (S_LEN - 1);
        if (sel == 0) {
          int h = n >> 7, d = n & 127;
          Qb[(((size_t)b * NH + h) * S_LEN + s) * HD + d] = v;
        } else if (sel == 1) {
          int nl = n - 4096;
          int h = nl >> 7, d = nl & 127;
          Kb[(((size_t)b * NKV + h) * S_LEN + s) * HD + d] = v;
        } else {
          int nl = n - 5120;
          int h = nl >> 7, d = nl & 127;
          Vt[(((size_t)b * NKV + h) * HD + d) * S_LEN + s] = v;  // transposed
        }
      }
    }
  }
}

// ---------------------------------------------------------------------------
// RoPE in-place on bf16 Q and K (V untouched). cos/sin halves identical.
// ---------------------------------------------------------------------------
__global__ __launch_bounds__(256) void rope_kernel(
    __bf16* __restrict__ Qb, __bf16* __restrict__ Kb,
    const float* __restrict__ cosp, const float* __restrict__ sinp)
{
  size_t i = (size_t)blockIdx.x * 256 + threadIdx.x;
  const size_t QP = (size_t)2 * NH * S_LEN * 64;  // 8388608 Q pairs
  __bf16* buf; int H; size_t t;
  if (i < QP) { buf = Qb; H = NH;  t = i; }
  else        { buf = Kb; H = NKV; t = i - QP; }
  int d = (int)(t & 63);
  int s = (int)((t >> 6) & (S_LEN - 1));
  size_t rest = t >> 17;            // / (S*64)
  int h = (int)(rest % H);
  int b = (int)(rest / H);
  size_t base = (((size_t)b * H + h) * S_LEN + s) * HD;
  float q0 = (float)buf[base + d];
  float q1 = (float)buf[base + d + 64];
  float c  = cosp[((size_t)b * S_LEN + s) * HD + d];
  float sn = sinp[((size_t)b * S_LEN + s) * HD + d];
  buf[base + d]      = (__bf16)(q0 * c - q1 * sn);
  buf[base + d + 64] = (__bf16)(q1 * c + q0 * sn);
}

// ---------------------------------------------------------------------------
// Flash attention, causal, GQA.
// Block = 128 q-rows of one (b,h); 4 waves x 32 rows (2 subtiles of 16).
// Q fragments live in registers. K/V tiles of 64 kv staged via reg-prefetch
// (global loads issued before the barrier -> latency overlaps prev compute).
// V arrives pre-transposed (Vt[d][s]) -> b128 LDS stores, no scalar transpose.
// Longest blocks (high qt) dispatch first: qt = 15 - blockIdx.y.
// LDS = 17.4K (Ks) + 18.4K (VTs) + 18.4K (Ps) = 54.2 KB -> 2 blocks/CU.
// ---------------------------------------------------------------------------
__global__ __launch_bounds__(256, 2) void flash_attn(
    const __bf16* __restrict__ Q, const __bf16* __restrict__ Kc,
    const __bf16* __restrict__ Vt, __bf16* __restrict__ Out)
{
  __shared__ __bf16 Ks[64 * 136];     // 272B stride: 2-way on b128 = ok
  __shared__ __bf16 VTs[128 * 72];    // [d][kv], 144B stride
  __shared__ __bf16 Ps[4 * 32 * 72];  // per-wave P buffer, 32 rows
  const int tid  = threadIdx.x;
  const int wave = tid >> 6, lane = tid & 63;
  const int quad = lane >> 4, l16 = lane & 15;
  const int bh = blockIdx.x;
  const int h = bh & 31, b = bh >> 5;
  const int qt = 15 - (int)blockIdx.y;   // reversed: longest first
  const int kvh = h >> 2;                // N_REP = 4
  const size_t qbase  = (((size_t)b * NH + h) * S_LEN + qt * 128 + wave * 32) * HD;
  const size_t kbase  = ((size_t)b * NKV + kvh) * S_LEN * HD;
  const size_t vtbase = ((size_t)b * NKV + kvh) * (size_t)HD * S_LEN;

  // Q fragments in registers: 2 subtiles x 4 k-steps
  bf16x8 qf[2][4];
  #pragma unroll
  for (int st = 0; st < 2; st++)
    #pragma unroll
    for (int kk = 0; kk < 4; kk++)
      qf[st][kk] = *(const bf16x8*)&Q[qbase + (size_t)(st * 16 + l16) * HD + kk * 32 + quad * 8];

  floatx4 o[2][8];
  #pragma unroll
  for (int st = 0; st < 2; st++)
    #pragma unroll
    for (int ct = 0; ct < 8; ct++) o[st][ct] = (floatx4){0.f, 0.f, 0.f, 0.f};
  float m_i[2][4], l_i[2][4];
  #pragma unroll
  for (int st = 0; st < 2; st++)
    #pragma unroll
    for (int r = 0; r < 4; r++) { m_i[st][r] = -3.0e38f; l_i[st][r] = 0.f; }

  const float scale = 0.08838834764831845f;  // 128^-0.5
  const int kj_end = 2 * qt + 2;

  for (int kj = 0; kj < kj_end; ++kj) {
    // --- prefetch K/V tile into registers (overlaps previous iter's compute)
    bf16x8 kreg[4], vreg[4];
    #pragma unroll
    for (int it = 0; it < 4; ++it) {
      int c = tid + it * 256;
      kreg[it] = *(const bf16x8*)&Kc[kbase + (size_t)(kj * 64 + (c >> 4)) * HD + (c & 15) * 8];
    }
    #pragma unroll
    for (int it = 0; it < 4; ++it) {
      int c = tid + it * 256;
      vreg[it] = *(const bf16x8*)&Vt[vtbase + (size_t)(c >> 3) * S_LEN + kj * 64 + (c & 7) * 8];
    }
    __syncthreads();  // prev iteration done reading LDS
    #pragma unroll
    for (int it = 0; it < 4; ++it) {
      int c = tid + it * 256;
      *(bf16x8*)&Ks[(c >> 4) * 136 + (c & 15) * 8] = kreg[it];
    }
    #pragma unroll
    for (int it = 0; it < 4; ++it) {
      int c = tid + it * 256;
      *(bf16x8*)&VTs[(c >> 3) * 72 + (c & 7) * 8] = vreg[it];
    }
    __syncthreads();

    // --- scores: 32 q-rows x 64 kv, K-dim 128 = 4 MFMA k-steps (bk shared by both st)
    floatx4 s[2][4];
    #pragma unroll
    for (int st = 0; st < 2; st++)
      #pragma unroll
      for (int j = 0; j < 4; j++) s[st][j] = (floatx4){0.f, 0.f, 0.f, 0.f};
    #pragma unroll
    for (int kk = 0; kk < 4; kk++) {
      bf16x8 bk[4];
      #pragma unroll
      for (int j = 0; j < 4; j++)
        bk[j] = *(const bf16x8*)&Ks[(j * 16 + l16) * 136 + kk * 32 + quad * 8];
      #pragma unroll
      for (int st = 0; st < 2; st++)
        #pragma unroll
        for (int j = 0; j < 4; j++)
          s[st][j] = __builtin_amdgcn_mfma_f32_16x16x32_bf16(qf[st][kk], bk[j], s[st][j], 0, 0, 0);
    }

    // --- online softmax per subtile
    #pragma unroll
    for (int st = 0; st < 2; st++) {
      const int rowb = qt * 128 + wave * 32 + st * 16 + quad * 4;  // + r
      const bool msk = (kj * 64 + 63 > qt * 128 + wave * 32 + st * 16);
      float p[4][4];
      #pragma unroll
      for (int r = 0; r < 4; r++) {
        float mx = -3.0e38f;
        #pragma unroll
        for (int j = 0; j < 4; j++) {
          float v = s[st][j][r] * scale;
          if (msk) {
            int ki = kj * 64 + j * 16 + l16;
            if (ki > rowb + r) v = -1.0e9f;
          }
          p[j][r] = v;
          mx = fmaxf(mx, v);
        }
        #pragma unroll
        for (int off = 1; off < 16; off <<= 1) mx = fmaxf(mx, __shfl_xor(mx, off, 64));
        float mn = fmaxf(m_i[st][r], mx);
        float alpha = __expf(m_i[st][r] - mn);
        m_i[st][r] = mn;
        float rs = 0.f;
        #pragma unroll
        for (int j = 0; j < 4; j++) {
          float e = __expf(p[j][r] - mn);
          p[j][r] = e;
          rs += e;
        }
        #pragma unroll
        for (int off = 1; off < 16; off <<= 1) rs += __shfl_xor(rs, off, 64);
        l_i[st][r] = l_i[st][r] * alpha + rs;
        #pragma unroll
        for (int ct = 0; ct < 8; ct++) o[st][ct][r] *= alpha;
        #pragma unroll
        for (int j = 0; j < 4; j++)
          Ps[wave * (32 * 72) + (st * 16 + quad * 4 + r) * 72 + j * 16 + l16] = (__bf16)p[j][r];
      }
    }

    // --- PV: O(32x128) += P(32x64) * V(64x128); bv shared by both subtiles
    #pragma unroll
    for (int kk = 0; kk < 2; kk++) {
      bf16x8 bv[8];
      #pragma unroll
      for (int ct = 0; ct < 8; ct++)
        bv[ct] = *(const bf16x8*)&VTs[(ct * 16 + l16) * 72 + kk * 32 + quad * 8];
      #pragma unroll
      for (int st = 0; st < 2; st++) {
        bf16x8 ap = *(const bf16x8*)&Ps[wave * (32 * 72) + (st * 16 + l16) * 72 + kk * 32 + quad * 8];
        #pragma unroll
        for (int ct = 0; ct < 8; ct++)
          o[st][ct] = __builtin_amdgcn_mfma_f32_16x16x32_bf16(ap, bv[ct], o[st][ct], 0, 0, 0);
      }
    }
  }

  // --- epilogue: attn_out[b][s][h*128+d] bf16
  #pragma unroll
  for (int st = 0; st < 2; st++) {
    #pragma unroll
    for (int r = 0; r < 4; r++) {
      float rl = 1.0f / l_i[st][r];
      int qi = qt * 128 + wave * 32 + st * 16 + quad * 4 + r;
      #pragma unroll
      for (int ct = 0; ct < 8; ct++) {
        Out[((size_t)b * S_LEN + qi) * HIDN + h * HD + ct * 16 + l16] =
            (__bf16)(o[st][ct][r] * rl);
      }
    }
  }
}

// ---------------------------------------------------------------------------
// Output GEMM: out(m,n) = sum_k attn_out[m][k] * Wo[n][k]; bf16 A, fp32 Wo->bf16.
// ---------------------------------------------------------------------------
__global__ __launch_bounds__(256) void out_gemm(
    const __bf16* __restrict__ A, const float* __restrict__ Wo,
    float* __restrict__ C)
{
  __shared__ __bf16 As[128 * 40];
  __shared__ __bf16 Bs[128 * 40];
  const int tid  = threadIdx.x;
  const int wave = tid >> 6, lane = tid & 63;
  const int quad = lane >> 4, l16 = lane & 15;
  const int wrow = (wave >> 1) * 64, wcol = (wave & 1) * 64;
  const int m0 = blockIdx.y * 128;
  const int n0 = blockIdx.x * 128;

  floatx4 acc[4][4];
  #pragma unroll
  for (int i = 0; i < 4; i++)
    #pragma unroll
    for (int j = 0; j < 4; j++) acc[i][j] = (floatx4){0.f, 0.f, 0.f, 0.f};

  for (int k0 = 0; k0 < HIDN; k0 += 32) {
    __syncthreads();
    #pragma unroll
    for (int it = 0; it < 2; ++it) {  // A tile: 512 bf16x8 chunks
      int c = tid + it * 256;
      int row = c >> 2, c8 = (c & 3) * 8;
      *(bf16x8*)&As[row * 40 + c8] =
          *(const bf16x8*)(A + (size_t)(m0 + row) * HIDN + k0 + c8);
    }
    #pragma unroll
    for (int it = 0; it < 4; ++it) {  // Wo tile: fp32 -> bf16
      int c = tid + it * 256;
      int row = c >> 3, c4 = (c & 7) * 4;
      float4 vb = *(const float4*)(Wo + (size_t)(n0 + row) * HIDN + k0 + c4);
      __bf16* db = &Bs[row * 40 + c4];
      db[0] = (__bf16)vb.x; db[1] = (__bf16)vb.y; db[2] = (__bf16)vb.z; db[3] = (__bf16)vb.w;
    }
    __syncthreads();
    bf16x8 af[4], bfr[4];
    #pragma unroll
    for (int i = 0; i < 4; i++)
      af[i] = *(const bf16x8*)&As[(wrow + i * 16 + l16) * 40 + quad * 8];
    #pragma unroll
    for (int j = 0; j < 4; j++)
      bfr[j] = *(const bf16x8*)&Bs[(wcol + j * 16 + l16) * 40 + quad * 8];
    #pragma unroll
    for (int i = 0; i < 4; i++)
      #pragma unroll
      for (int j = 0; j < 4; j++)
        acc[i][j] = __builtin_amdgcn_mfma_f32_16x16x32_bf16(af[i], bfr[j], acc[i][j], 0, 0, 0);
  }

  #pragma unroll
  for (int i = 0; i < 4; i++)
    #pragma unroll
    for (int j = 0; j < 4; j++)
      #pragma unroll
      for (int r = 0; r < 4; r++) {
        int m = m0 + wrow + i * 16 + quad * 4 + r;
        int n = n0 + wcol + j * 16 + l16;
        C[(size_t)m * HIDN + n] = acc[i][j][r];
      }
}

// ---------------------------------------------------------------------------
extern "C" void kernel_launch(void* const* d_in, const int* in_sizes, int n_in,
                              void* d_out, int out_size, void* d_ws, size_t ws_size,
                              hipStream_t stream)
{
  const float* hs   = (const float*)d_in[0];
  const float* cosp = (const float*)d_in[1];
  const float* sinp = (const float*)d_in[2];
  // d_in[3] = attention_mask: exactly causal -1e9, applied analytically in flash_attn
  const float* Wq   = (const float*)d_in[4];
  const float* Wk   = (const float*)d_in[5];
  const float* Wv   = (const float*)d_in[6];
  const float* Wo   = (const float*)d_in[7];
  float* out = (float*)d_out;

  __bf16* Qb = (__bf16*)d_ws;                          // 16,777,216 elems
  __bf16* Kb = Qb + (size_t)2 * NH  * S_LEN * HD;      //  4,194,304
  __bf16* Vtb = Kb + (size_t)2 * NKV * S_LEN * HD;     //  4,194,304 (transposed)
  __bf16* AO = Vtb + (size_t)2 * NKV * S_LEN * HD;     // 16,777,216  (total 80 MB)

  qkv_gemm<<<dim3(48, 32), 256, 0, stream>>>(hs, Wq, Wk, Wv, Qb, Kb, Vtb);
  rope_kernel<<<40960, 256, 0, stream>>>(Qb, Kb, cosp, sinp);
  flash_attn<<<dim3(64, 16), 256, 0, stream>>>(Qb, Kb, Vtb, AO);
  out_gemm<<<dim3(32, 32), 256, 0, stream>>>(AO, Wo, out);
}

// Round 3
// 852.760 us; speedup vs baseline: 1.5485x; 1.1956x over previous
//
#include <hip/hip_runtime.h>

// LlamaAttention: B=2, S=2048, HID=4096, NH=32, NKV=8, HD=128, GQA rep=4, RoPE, causal.
// Fast path (ws >= 128MB): cvt(hs,Wqkv)->bf16 | qkv_gemm_bf16 (global_load_lds, m97-style)
//   | cvt(Wo) (aliased over dead Wqkv) | rope | flash_attn | out_gemm_bf16.
// Fallback (ws < 128MB): round-1 kernels (fp32 weights converted in-staging).
//
// ws layout (bf16 elems), fast path:
//   Q[16777216] K[4194304] Vt[4194304] HSB/AO alias[16777216] WB[25165824]
//   = 67,108,864 elems = 128 MB exactly.

typedef __bf16 bf16x8 __attribute__((ext_vector_type(8)));
typedef float floatx4 __attribute__((ext_vector_type(4)));

#define S_LEN 2048
#define HIDN  4096
#define NH    32
#define NKV   8
#define HD    128

__device__ inline void async_copy16(const void* g, void* l) {
  __builtin_amdgcn_global_load_lds(
      (const __attribute__((address_space(1))) void*)g,
      (__attribute__((address_space(3))) void*)l, 16, 0, 0);
}

// ---------------------------------------------------------------------------
// fp32 -> bf16 bulk convert: 8 elems/thread (2x float4 read, 16B write).
// ---------------------------------------------------------------------------
__global__ __launch_bounds__(256) void cvt_bf16(const float* __restrict__ src,
                                                __bf16* __restrict__ dst, int n8)
{
  int i = blockIdx.x * 256 + threadIdx.x;
  if (i >= n8) return;
  const float4* s = (const float4*)src + (size_t)i * 2;
  float4 a = s[0], b = s[1];
  bf16x8 r = {(__bf16)a.x, (__bf16)a.y, (__bf16)a.z, (__bf16)a.w,
              (__bf16)b.x, (__bf16)b.y, (__bf16)b.z, (__bf16)b.w};
  *((bf16x8*)dst + i) = r;
}

// ---------------------------------------------------------------------------
// FAST QKV GEMM (bf16 in): C(m,n) = sum_k hsb[m][k] * WB[n][k], n in [0,6144).
// m97 structure: 128x128 tile, BK=32, global_load_lds width 16, unpadded LDS.
// Scatter epilogue: Q (b,h,s,d), K (b,kh,s,d), V transposed (b,kh,d,s).
// ---------------------------------------------------------------------------
__global__ __launch_bounds__(256) void qkv_gemm_bf16(
    const __bf16* __restrict__ A, const __bf16* __restrict__ WB,
    __bf16* __restrict__ Qb, __bf16* __restrict__ Kb, __bf16* __restrict__ Vt)
{
  __shared__ __bf16 As[128 * 32];   // 8 KB, unpadded (global_load_lds order)
  __shared__ __bf16 Bs[128 * 32];
  const int tid  = threadIdx.x;
  const int wave = tid >> 6, lane = tid & 63;
  const int quad = lane >> 4, l16 = lane & 15;
  const int ln4  = lane >> 2;        // 0..15: row within 16-row chunk
  const int kc   = (lane & 3) * 8;   // element offset within 32-K
  const int wrow = (wave >> 1) * 64, wcol = (wave & 1) * 64;
  const int m0 = blockIdx.y * 128;
  const int n0 = blockIdx.x * 128;

  floatx4 acc[4][4];
  #pragma unroll
  for (int i = 0; i < 4; i++)
    #pragma unroll
    for (int j = 0; j < 4; j++) acc[i][j] = (floatx4){0.f, 0.f, 0.f, 0.f};

  for (int k0 = 0; k0 < HIDN; k0 += 32) {
    __syncthreads();  // WAR: prev iter done reading LDS
    #pragma unroll
    for (int c = 0; c < 2; ++c) {
      int ch = wave * 2 + c;         // 0..7 chunks of 16 rows
      int row = ch * 16 + ln4;
      async_copy16(A  + (size_t)(m0 + row) * HIDN + k0 + kc, &As[ch * 512 + lane * 8]);
      async_copy16(WB + (size_t)(n0 + row) * HIDN + k0 + kc, &Bs[ch * 512 + lane * 8]);
    }
    __syncthreads();  // compiler drains vmcnt(0) before barrier -> LDS visible

    bf16x8 af[4], bfr[4];
    #pragma unroll
    for (int i = 0; i < 4; i++)
      af[i] = *(const bf16x8*)&As[(wrow + i * 16 + l16) * 32 + quad * 8];
    #pragma unroll
    for (int j = 0; j < 4; j++)
      bfr[j] = *(const bf16x8*)&Bs[(wcol + j * 16 + l16) * 32 + quad * 8];
    #pragma unroll
    for (int i = 0; i < 4; i++)
      #pragma unroll
      for (int j = 0; j < 4; j++)
        acc[i][j] = __builtin_amdgcn_mfma_f32_16x16x32_bf16(af[i], bfr[j], acc[i][j], 0, 0, 0);
  }

  #pragma unroll
  for (int i = 0; i < 4; i++) {
    #pragma unroll
    for (int j = 0; j < 4; j++) {
      #pragma unroll
      for (int r = 0; r < 4; r++) {
        int m = m0 + wrow + i * 16 + quad * 4 + r;
        int n = n0 + wcol + j * 16 + l16;
        __bf16 v = (__bf16)acc[i][j][r];
        int b = m >> 11, s = m & (S_LEN - 1);
        if (n < 4096) {
          int h = n >> 7, d = n & 127;
          Qb[(((size_t)b * NH + h) * S_LEN + s) * HD + d] = v;
        } else if (n < 5120) {
          int nl = n - 4096, h = nl >> 7, d = nl & 127;
          Kb[(((size_t)b * NKV + h) * S_LEN + s) * HD + d] = v;
        } else {
          int nl = n - 5120, h = nl >> 7, d = nl & 127;
          Vt[(((size_t)b * NKV + h) * HD + d) * S_LEN + s] = v;  // transposed
        }
      }
    }
  }
}

// ---------------------------------------------------------------------------
// FAST OUT GEMM (bf16 in, fp32 out): out(m,n) = sum_k AO[m][k] * WoB[n][k].
// ---------------------------------------------------------------------------
__global__ __launch_bounds__(256) void out_gemm_bf16(
    const __bf16* __restrict__ A, const __bf16* __restrict__ WB,
    float* __restrict__ C)
{
  __shared__ __bf16 As[128 * 32];
  __shared__ __bf16 Bs[128 * 32];
  const int tid  = threadIdx.x;
  const int wave = tid >> 6, lane = tid & 63;
  const int quad = lane >> 4, l16 = lane & 15;
  const int ln4  = lane >> 2;
  const int kc   = (lane & 3) * 8;
  const int wrow = (wave >> 1) * 64, wcol = (wave & 1) * 64;
  const int m0 = blockIdx.y * 128;
  const int n0 = blockIdx.x * 128;

  floatx4 acc[4][4];
  #pragma unroll
  for (int i = 0; i < 4; i++)
    #pragma unroll
    for (int j = 0; j < 4; j++) acc[i][j] = (floatx4){0.f, 0.f, 0.f, 0.f};

  for (int k0 = 0; k0 < HIDN; k0 += 32) {
    __syncthreads();
    #pragma unroll
    for (int c = 0; c < 2; ++c) {
      int ch = wave * 2 + c;
      int row = ch * 16 + ln4;
      async_copy16(A  + (size_t)(m0 + row) * HIDN + k0 + kc, &As[ch * 512 + lane * 8]);
      async_copy16(WB + (size_t)(n0 + row) * HIDN + k0 + kc, &Bs[ch * 512 + lane * 8]);
    }
    __syncthreads();

    bf16x8 af[4], bfr[4];
    #pragma unroll
    for (int i = 0; i < 4; i++)
      af[i] = *(const bf16x8*)&As[(wrow + i * 16 + l16) * 32 + quad * 8];
    #pragma unroll
    for (int j = 0; j < 4; j++)
      bfr[j] = *(const bf16x8*)&Bs[(wcol + j * 16 + l16) * 32 + quad * 8];
    #pragma unroll
    for (int i = 0; i < 4; i++)
      #pragma unroll
      for (int j = 0; j < 4; j++)
        acc[i][j] = __builtin_amdgcn_mfma_f32_16x16x32_bf16(af[i], bfr[j], acc[i][j], 0, 0, 0);
  }

  #pragma unroll
  for (int i = 0; i < 4; i++)
    #pragma unroll
    for (int j = 0; j < 4; j++)
      #pragma unroll
      for (int r = 0; r < 4; r++) {
        int m = m0 + wrow + i * 16 + quad * 4 + r;
        int n = n0 + wcol + j * 16 + l16;
        C[(size_t)m * HIDN + n] = acc[i][j][r];
      }
}

// ---------------------------------------------------------------------------
// FALLBACK QKV GEMM (fp32 in, convert in staging) — round-1 version.
// ---------------------------------------------------------------------------
__global__ __launch_bounds__(256) void qkv_gemm_f32(
    const float* __restrict__ A, const float* __restrict__ Wq,
    const float* __restrict__ Wk, const float* __restrict__ Wv,
    __bf16* __restrict__ Qb, __bf16* __restrict__ Kb, __bf16* __restrict__ Vt)
{
  __shared__ __bf16 As[128 * 40];
  __shared__ __bf16 Bs[128 * 40];
  const int tid  = threadIdx.x;
  const int wave = tid >> 6, lane = tid & 63;
  const int quad = lane >> 4, l16 = lane & 15;
  const int wrow = (wave >> 1) * 64, wcol = (wave & 1) * 64;
  const int m0 = blockIdx.y * 128;
  const int n0 = blockIdx.x * 128;

  const float* W; int wr0; int sel;
  if (n0 < 4096)      { W = Wq; wr0 = n0;        sel = 0; }
  else if (n0 < 5120) { W = Wk; wr0 = n0 - 4096; sel = 1; }
  else                { W = Wv; wr0 = n0 - 5120; sel = 2; }

  floatx4 acc[4][4];
  #pragma unroll
  for (int i = 0; i < 4; i++)
    #pragma unroll
    for (int j = 0; j < 4; j++) acc[i][j] = (floatx4){0.f, 0.f, 0.f, 0.f};

  for (int k0 = 0; k0 < HIDN; k0 += 32) {
    __syncthreads();
    #pragma unroll
    for (int it = 0; it < 4; ++it) {
      int c = tid + it * 256;
      int row = c >> 3, c4 = (c & 7) * 4;
      float4 va = *(const float4*)(A + (size_t)(m0 + row) * HIDN + k0 + c4);
      __bf16* da = &As[row * 40 + c4];
      da[0] = (__bf16)va.x; da[1] = (__bf16)va.y; da[2] = (__bf16)va.z; da[3] = (__bf16)va.w;
      float4 vb = *(const float4*)(W + (size_t)(wr0 + row) * HIDN + k0 + c4);
      __bf16* db = &Bs[row * 40 + c4];
      db[0] = (__bf16)vb.x; db[1] = (__bf16)vb.y; db[2] = (__bf16)vb.z; db[3] = (__bf16)vb.w;
    }
    __syncthreads();
    bf16x8 af[4], bfr[4];
    #pragma unroll
    for (int i = 0; i < 4; i++)
      af[i] = *(const bf16x8*)&As[(wrow + i * 16 + l16) * 40 + quad * 8];
    #pragma unroll
    for (int j = 0; j < 4; j++)
      bfr[j] = *(const bf16x8*)&Bs[(wcol + j * 16 + l16) * 40 + quad * 8];
    #pragma unroll
    for (int i = 0; i < 4; i++)
      #pragma unroll
      for (int j = 0; j < 4; j++)
        acc[i][j] = __builtin_amdgcn_mfma_f32_16x16x32_bf16(af[i], bfr[j], acc[i][j], 0, 0, 0);
  }

  #pragma unroll
  for (int i = 0; i < 4; i++) {
    #pragma unroll
    for (int j = 0; j < 4; j++) {
      #pragma unroll
      for (int r = 0; r < 4; r++) {
        int m = m0 + wrow + i * 16 + quad * 4 + r;
        int n = n0 + wcol + j * 16 + l16;
        __bf16 v = (__bf16)acc[i][j][r];
        int b = m >> 11, s = m & (S_LEN - 1);
        if (sel == 0) {
          int h = n >> 7, d = n & 127;
          Qb[(((size_t)b * NH + h) * S_LEN + s) * HD + d] = v;
        } else if (sel == 1) {
          int nl = n - 4096, h = nl >> 7, d = nl & 127;
          Kb[(((size_t)b * NKV + h) * S_LEN + s) * HD + d] = v;
        } else {
          int nl = n - 5120, h = nl >> 7, d = nl & 127;
          Vt[(((size_t)b * NKV + h) * HD + d) * S_LEN + s] = v;
        }
      }
    }
  }
}

// ---------------------------------------------------------------------------
// FALLBACK OUT GEMM (fp32 Wo converted in staging) — round-1 version.
// ---------------------------------------------------------------------------
__global__ __launch_bounds__(256) void out_gemm_f32(
    const __bf16* __restrict__ A, const float* __restrict__ Wo,
    float* __restrict__ C)
{
  __shared__ __bf16 As[128 * 40];
  __shared__ __bf16 Bs[128 * 40];
  const int tid  = threadIdx.x;
  const int wave = tid >> 6, lane = tid & 63;
  const int quad = lane >> 4, l16 = lane & 15;
  const int wrow = (wave >> 1) * 64, wcol = (wave & 1) * 64;
  const int m0 = blockIdx.y * 128;
  const int n0 = blockIdx.x * 128;

  floatx4 acc[4][4];
  #pragma unroll
  for (int i = 0; i < 4; i++)
    #pragma unroll
    for (int j = 0; j < 4; j++) acc[i][j] = (floatx4){0.f, 0.f, 0.f, 0.f};

  for (int k0 = 0; k0 < HIDN; k0 += 32) {
    __syncthreads();
    #pragma unroll
    for (int it = 0; it < 2; ++it) {
      int c = tid + it * 256;
      int row = c >> 2, c8 = (c & 3) * 8;
      *(bf16x8*)&As[row * 40 + c8] =
          *(const bf16x8*)(A + (size_t)(m0 + row) * HIDN + k0 + c8);
    }
    #pragma unroll
    for (int it = 0; it < 4; ++it) {
      int c = tid + it * 256;
      int row = c >> 3, c4 = (c & 7) * 4;
      float4 vb = *(const float4*)(Wo + (size_t)(n0 + row) * HIDN + k0 + c4);
      __bf16* db = &Bs[row * 40 + c4];
      db[0] = (__bf16)vb.x; db[1] = (__bf16)vb.y; db[2] = (__bf16)vb.z; db[3] = (__bf16)vb.w;
    }
    __syncthreads();
    bf16x8 af[4], bfr[4];
    #pragma unroll
    for (int i = 0; i < 4; i++)
      af[i] = *(const bf16x8*)&As[(wrow + i * 16 + l16) * 40 + quad * 8];
    #pragma unroll
    for (int j = 0; j < 4; j++)
      bfr[j] = *(const bf16x8*)&Bs[(wcol + j * 16 + l16) * 40 + quad * 8];
    #pragma unroll
    for (int i = 0; i < 4; i++)
      #pragma unroll
      for (int j = 0; j < 4; j++)
        acc[i][j] = __builtin_amdgcn_mfma_f32_16x16x32_bf16(af[i], bfr[j], acc[i][j], 0, 0, 0);
  }

  #pragma unroll
  for (int i = 0; i < 4; i++)
    #pragma unroll
    for (int j = 0; j < 4; j++)
      #pragma unroll
      for (int r = 0; r < 4; r++) {
        int m = m0 + wrow + i * 16 + quad * 4 + r;
        int n = n0 + wcol + j * 16 + l16;
        C[(size_t)m * HIDN + n] = acc[i][j][r];
      }
}

// ---------------------------------------------------------------------------
// RoPE in-place on bf16 Q and K (V untouched). cos/sin halves identical.
// ---------------------------------------------------------------------------
__global__ __launch_bounds__(256) void rope_kernel(
    __bf16* __restrict__ Qb, __bf16* __restrict__ Kb,
    const float* __restrict__ cosp, const float* __restrict__ sinp)
{
  size_t i = (size_t)blockIdx.x * 256 + threadIdx.x;
  const size_t QP = (size_t)2 * NH * S_LEN * 64;  // 8388608 Q pairs
  __bf16* buf; int H; size_t t;
  if (i < QP) { buf = Qb; H = NH;  t = i; }
  else        { buf = Kb; H = NKV; t = i - QP; }
  int d = (int)(t & 63);
  int s = (int)((t >> 6) & (S_LEN - 1));
  size_t rest = t >> 17;
  int h = (int)(rest % H);
  int b = (int)(rest / H);
  size_t base = (((size_t)b * H + h) * S_LEN + s) * HD;
  float q0 = (float)buf[base + d];
  float q1 = (float)buf[base + d + 64];
  float c  = cosp[((size_t)b * S_LEN + s) * HD + d];
  float sn = sinp[((size_t)b * S_LEN + s) * HD + d];
  buf[base + d]      = (__bf16)(q0 * c - q1 * sn);
  buf[base + d + 64] = (__bf16)(q1 * c + q0 * sn);
}

// ---------------------------------------------------------------------------
// Flash attention, causal, GQA. (unchanged from round 1 — verified)
// ---------------------------------------------------------------------------
__global__ __launch_bounds__(256, 2) void flash_attn(
    const __bf16* __restrict__ Q, const __bf16* __restrict__ Kc,
    const __bf16* __restrict__ Vt, __bf16* __restrict__ Out)
{
  __shared__ __bf16 Ks[64 * 136];
  __shared__ __bf16 VTs[128 * 72];
  __shared__ __bf16 Ps[4 * 32 * 72];
  const int tid  = threadIdx.x;
  const int wave = tid >> 6, lane = tid & 63;
  const int quad = lane >> 4, l16 = lane & 15;
  const int bh = blockIdx.x;
  const int h = bh & 31, b = bh >> 5;
  const int qt = 15 - (int)blockIdx.y;
  const int kvh = h >> 2;
  const size_t qbase  = (((size_t)b * NH + h) * S_LEN + qt * 128 + wave * 32) * HD;
  const size_t kbase  = ((size_t)b * NKV + kvh) * S_LEN * HD;
  const size_t vtbase = ((size_t)b * NKV + kvh) * (size_t)HD * S_LEN;

  bf16x8 qf[2][4];
  #pragma unroll
  for (int st = 0; st < 2; st++)
    #pragma unroll
    for (int kk = 0; kk < 4; kk++)
      qf[st][kk] = *(const bf16x8*)&Q[qbase + (size_t)(st * 16 + l16) * HD + kk * 32 + quad * 8];

  floatx4 o[2][8];
  #pragma unroll
  for (int st = 0; st < 2; st++)
    #pragma unroll
    for (int ct = 0; ct < 8; ct++) o[st][ct] = (floatx4){0.f, 0.f, 0.f, 0.f};
  float m_i[2][4], l_i[2][4];
  #pragma unroll
  for (int st = 0; st < 2; st++)
    #pragma unroll
    for (int r = 0; r < 4; r++) { m_i[st][r] = -3.0e38f; l_i[st][r] = 0.f; }

  const float scale = 0.08838834764831845f;
  const int kj_end = 2 * qt + 2;

  for (int kj = 0; kj < kj_end; ++kj) {
    bf16x8 kreg[4], vreg[4];
    #pragma unroll
    for (int it = 0; it < 4; ++it) {
      int c = tid + it * 256;
      kreg[it] = *(const bf16x8*)&Kc[kbase + (size_t)(kj * 64 + (c >> 4)) * HD + (c & 15) * 8];
    }
    #pragma unroll
    for (int it = 0; it < 4; ++it) {
      int c = tid + it * 256;
      vreg[it] = *(const bf16x8*)&Vt[vtbase + (size_t)(c >> 3) * S_LEN + kj * 64 + (c & 7) * 8];
    }
    __syncthreads();
    #pragma unroll
    for (int it = 0; it < 4; ++it) {
      int c = tid + it * 256;
      *(bf16x8*)&Ks[(c >> 4) * 136 + (c & 15) * 8] = kreg[it];
    }
    #pragma unroll
    for (int it = 0; it < 4; ++it) {
      int c = tid + it * 256;
      *(bf16x8*)&VTs[(c >> 3) * 72 + (c & 7) * 8] = vreg[it];
    }
    __syncthreads();

    floatx4 s[2][4];
    #pragma unroll
    for (int st = 0; st < 2; st++)
      #pragma unroll
      for (int j = 0; j < 4; j++) s[st][j] = (floatx4){0.f, 0.f, 0.f, 0.f};
    #pragma unroll
    for (int kk = 0; kk < 4; kk++) {
      bf16x8 bk[4];
      #pragma unroll
      for (int j = 0; j < 4; j++)
        bk[j] = *(const bf16x8*)&Ks[(j * 16 + l16) * 136 + kk * 32 + quad * 8];
      #pragma unroll
      for (int st = 0; st < 2; st++)
        #pragma unroll
        for (int j = 0; j < 4; j++)
          s[st][j] = __builtin_amdgcn_mfma_f32_16x16x32_bf16(qf[st][kk], bk[j], s[st][j], 0, 0, 0);
    }

    #pragma unroll
    for (int st = 0; st < 2; st++) {
      const int rowb = qt * 128 + wave * 32 + st * 16 + quad * 4;
      const bool msk = (kj * 64 + 63 > qt * 128 + wave * 32 + st * 16);
      float p[4][4];
      #pragma unroll
      for (int r = 0; r < 4; r++) {
        float mx = -3.0e38f;
        #pragma unroll
        for (int j = 0; j < 4; j++) {
          float v = s[st][j][r] * scale;
          if (msk) {
            int ki = kj * 64 + j * 16 + l16;
            if (ki > rowb + r) v = -1.0e9f;
          }
          p[j][r] = v;
          mx = fmaxf(mx, v);
        }
        #pragma unroll
        for (int off = 1; off < 16; off <<= 1) mx = fmaxf(mx, __shfl_xor(mx, off, 64));
        float mn = fmaxf(m_i[st][r], mx);
        float alpha = __expf(m_i[st][r] - mn);
        m_i[st][r] = mn;
        float rs = 0.f;
        #pragma unroll
        for (int j = 0; j < 4; j++) {
          float e = __expf(p[j][r] - mn);
          p[j][r] = e;
          rs += e;
        }
        #pragma unroll
        for (int off = 1; off < 16; off <<= 1) rs += __shfl_xor(rs, off, 64);
        l_i[st][r] = l_i[st][r] * alpha + rs;
        #pragma unroll
        for (int ct = 0; ct < 8; ct++) o[st][ct][r] *= alpha;
        #pragma unroll
        for (int j = 0; j < 4; j++)
          Ps[wave * (32 * 72) + (st * 16 + quad * 4 + r) * 72 + j * 16 + l16] = (__bf16)p[j][r];
      }
    }

    #pragma unroll
    for (int kk = 0; kk < 2; kk++) {
      bf16x8 bv[8];
      #pragma unroll
      for (int ct = 0; ct < 8; ct++)
        bv[ct] = *(const bf16x8*)&VTs[(ct * 16 + l16) * 72 + kk * 32 + quad * 8];
      #pragma unroll
      for (int st = 0; st < 2; st++) {
        bf16x8 ap = *(const bf16x8*)&Ps[wave * (32 * 72) + (st * 16 + l16) * 72 + kk * 32 + quad * 8];
        #pragma unroll
        for (int ct = 0; ct < 8; ct++)
          o[st][ct] = __builtin_amdgcn_mfma_f32_16x16x32_bf16(ap, bv[ct], o[st][ct], 0, 0, 0);
      }
    }
  }

  #pragma unroll
  for (int st = 0; st < 2; st++) {
    #pragma unroll
    for (int r = 0; r < 4; r++) {
      float rl = 1.0f / l_i[st][r];
      int qi = qt * 128 + wave * 32 + st * 16 + quad * 4 + r;
      #pragma unroll
      for (int ct = 0; ct < 8; ct++) {
        Out[((size_t)b * S_LEN + qi) * HIDN + h * HD + ct * 16 + l16] =
            (__bf16)(o[st][ct][r] * rl);
      }
    }
  }
}

// ---------------------------------------------------------------------------
extern "C" void kernel_launch(void* const* d_in, const int* in_sizes, int n_in,
                              void* d_out, int out_size, void* d_ws, size_t ws_size,
                              hipStream_t stream)
{
  const float* hs   = (const float*)d_in[0];
  const float* cosp = (const float*)d_in[1];
  const float* sinp = (const float*)d_in[2];
  // d_in[3] = attention_mask: exactly causal -1e9, applied analytically in flash_attn
  const float* Wq   = (const float*)d_in[4];
  const float* Wk   = (const float*)d_in[5];
  const float* Wv   = (const float*)d_in[6];
  const float* Wo   = (const float*)d_in[7];
  float* out = (float*)d_out;

  __bf16* Qb  = (__bf16*)d_ws;                         // 16,777,216
  __bf16* Kb  = Qb  + (size_t)16777216;                //  4,194,304
  __bf16* Vtb = Kb  + (size_t)4194304;                 //  4,194,304

  if (ws_size >= (size_t)134217728) {
    // ---- fast path: pre-converted bf16 operands, global_load_lds GEMMs
    __bf16* HSB = Vtb + (size_t)4194304;   // hs bf16; aliased by AO after qkv
    __bf16* AO  = HSB;
    __bf16* WB  = HSB + (size_t)16777216;  // Wq|Wk|Wv bf16 (25,165,824); Wo aliases after qkv

    cvt_bf16<<<8192, 256, 0, stream>>>(hs, HSB, 2097152);
    cvt_bf16<<<8192, 256, 0, stream>>>(Wq, WB, 2097152);
    cvt_bf16<<<2048, 256, 0, stream>>>(Wk, WB + 16777216, 524288);
    cvt_bf16<<<2048, 256, 0, stream>>>(Wv, WB + 20971520, 524288);
    qkv_gemm_bf16<<<dim3(48, 32), 256, 0, stream>>>(HSB, WB, Qb, Kb, Vtb);
    cvt_bf16<<<8192, 256, 0, stream>>>(Wo, WB, 2097152);  // Wqkv dead now
    rope_kernel<<<40960, 256, 0, stream>>>(Qb, Kb, cosp, sinp);
    flash_attn<<<dim3(64, 16), 256, 0, stream>>>(Qb, Kb, Vtb, AO);
    out_gemm_bf16<<<dim3(32, 32), 256, 0, stream>>>(AO, WB, out);
  } else {
    // ---- fallback: round-1 pipeline (84 MB ws)
    __bf16* AO = Vtb + (size_t)4194304;
    qkv_gemm_f32<<<dim3(48, 32), 256, 0, stream>>>(hs, Wq, Wk, Wv, Qb, Kb, Vtb);
    rope_kernel<<<40960, 256, 0, stream>>>(Qb, Kb, cosp, sinp);
    flash_attn<<<dim3(64, 16), 256, 0, stream>>>(Qb, Kb, Vtb, AO);
    out_gemm_f32<<<dim3(32, 32), 256, 0, stream>>>(AO, Wo, out);
  }
}